// Round 2
// baseline (1275.140 us; speedup 1.0000x reference)
//
#include <hip/hip_runtime.h>

// VecInt: scaling-and-squaring integration of a stationary velocity field.
// vec' = vec/2^7; repeat 7x: vec = vec + grid_sample3d(vec, vec + ident).
// Fixed problem shape from setup_inputs(): (1, 3, 160, 192, 160) float32.
//
// Numerics note: the iteration is chaotic in the eps-amplification sense
// (value error -> coordinate error -> value error x local gradient, per step).
// To stay inside the harness threshold we do all per-step arithmetic in
// double and round only at the f32 store, so our divergence from the
// reference is just per-step storage quantization.

constexpr int D = 160;
constexpr int H = 192;
constexpr int W = 160;
constexpr int HW = H * W;        // 30720
constexpr int DHW = D * HW;      // 4915200
constexpr int NSTEPS = 7;        // nsteps is always 7 (harness restores pristine inputs)

__global__ __launch_bounds__(256)
void vecint_step(const float* __restrict__ src, float* __restrict__ dst, float s) {
    int p = blockIdx.x * blockDim.x + threadIdx.x;
    if (p >= DHW) return;

    int d   = p / HW;
    int rem = p - d * HW;
    int h   = rem / W;
    int w   = rem - h * W;

    // Displacement at this voxel (3 channels, coalesced f32 loads).
    double vz = (double)src[p];
    double vy = (double)src[p + DHW];
    double vx = (double)src[p + 2 * DHW];
    double sd = (double)s;

    // Unnormalized coords: (s*v + ident + 1)*0.5*(dim-1) = s*v*0.5*(dim-1) + idx
    double z = vz * (sd * 0.5 * (double)(D - 1)) + (double)d;
    double y = vy * (sd * 0.5 * (double)(H - 1)) + (double)h;
    double x = vx * (sd * 0.5 * (double)(W - 1)) + (double)w;

    double z0f = floor(z), y0f = floor(y), x0f = floor(x);
    int z0 = (int)z0f, y0 = (int)y0f, x0 = (int)x0f;
    int z1 = z0 + 1,   y1 = y0 + 1,   x1 = x0 + 1;
    double fz = z - z0f, fy = y - y0f, fx = x - x0f;

    // Zero-padding validity per axis index.
    bool zv0 = ((unsigned)z0 < (unsigned)D), zv1 = ((unsigned)z1 < (unsigned)D);
    bool yv0 = ((unsigned)y0 < (unsigned)H), yv1 = ((unsigned)y1 < (unsigned)H);
    bool xv0 = ((unsigned)x0 < (unsigned)W), xv1 = ((unsigned)x1 < (unsigned)W);

    // Clamped indices (loads always in-bounds; invalid corners get weight 0).
    int zc0 = min(max(z0, 0), D - 1), zc1 = min(max(z1, 0), D - 1);
    int yc0 = min(max(y0, 0), H - 1), yc1 = min(max(y1, 0), H - 1);
    int xc0 = min(max(x0, 0), W - 1), xc1 = min(max(x1, 0), W - 1);

    double wz0 = 1.0 - fz, wz1 = fz;
    double wy0 = 1.0 - fy, wy1 = fy;
    double wx0 = 1.0 - fx, wx1 = fx;

    double w000 = (zv0 && yv0 && xv0) ? wz0 * wy0 * wx0 : 0.0;
    double w001 = (zv0 && yv0 && xv1) ? wz0 * wy0 * wx1 : 0.0;
    double w010 = (zv0 && yv1 && xv0) ? wz0 * wy1 * wx0 : 0.0;
    double w011 = (zv0 && yv1 && xv1) ? wz0 * wy1 * wx1 : 0.0;
    double w100 = (zv1 && yv0 && xv0) ? wz1 * wy0 * wx0 : 0.0;
    double w101 = (zv1 && yv0 && xv1) ? wz1 * wy0 * wx1 : 0.0;
    double w110 = (zv1 && yv1 && xv0) ? wz1 * wy1 * wx0 : 0.0;
    double w111 = (zv1 && yv1 && xv1) ? wz1 * wy1 * wx1 : 0.0;

    int b00 = zc0 * HW + yc0 * W;
    int b01 = zc0 * HW + yc1 * W;
    int b10 = zc1 * HW + yc0 * W;
    int b11 = zc1 * HW + yc1 * W;

    int a000 = b00 + xc0, a001 = b00 + xc1;
    int a010 = b01 + xc0, a011 = b01 + xc1;
    int a100 = b10 + xc0, a101 = b10 + xc1;
    int a110 = b11 + xc0, a111 = b11 + xc1;

    #pragma unroll
    for (int c = 0; c < 3; ++c) {
        const float* sc = src + c * DHW;
        double acc = (double)sc[p];
        acc += w000 * (double)sc[a000];
        acc += w001 * (double)sc[a001];
        acc += w010 * (double)sc[a010];
        acc += w011 * (double)sc[a011];
        acc += w100 * (double)sc[a100];
        acc += w101 * (double)sc[a101];
        acc += w110 * (double)sc[a110];
        acc += w111 * (double)sc[a111];
        dst[c * DHW + p] = (float)(sd * acc);
    }
}

extern "C" void kernel_launch(void* const* d_in, const int* in_sizes, int n_in,
                              void* d_out, int out_size, void* d_ws, size_t ws_size,
                              hipStream_t stream) {
    const float* vin = (const float*)d_in[0];
    float* out = (float*)d_out;
    float* ws  = (float*)d_ws;

    const float s = 1.0f / 128.0f;  // 1/2^NSTEPS, NSTEPS=7 (exact power of 2)

    dim3 block(256);
    dim3 grid((DHW + 255) / 256);

    // Step 1: fold the initial scale in (exact for power-of-2 s), read
    // pristine input, write d_out.
    vecint_step<<<grid, block, 0, stream>>>(vin, out, s);

    // Steps 2..7: ping-pong d_out <-> d_ws; 6 more steps ends back in d_out.
    const float* srcs[6] = {out, ws, out, ws, out, ws};
    float*       dsts[6] = {ws, out, ws, out, ws, out};
    for (int i = 0; i < NSTEPS - 1; ++i) {
        vecint_step<<<grid, block, 0, stream>>>(srcs[i], dsts[i], 1.0f);
    }
}

// Round 3
// 975.928 us; speedup vs baseline: 1.3066x; 1.3066x over previous
//
#include <hip/hip_runtime.h>

// VecInt: scaling-and-squaring integration of a stationary velocity field.
// vec' = vec/2^7; repeat 7x: vec = vec + grid_sample3d(vec, vec + ident).
// Fixed problem shape from setup_inputs(): (1, 3, 160, 192, 160) float32.
//
// Numerics: per-step arithmetic in double, store f32 (divergence from np ref
// = per-step storage quantization only). absmax 4.39e-3 vs 5.16e-3 thr (R2).
//
// Locality: 3D tiles (32x8x1) + XCD-slab swizzle. R2 showed 4.7x read
// over-fetch (278 MB vs 59 MB ideal) with linear mapping — gathered rows
// missed L2 because round-robin block->XCD dispatch scattered z/y-adjacent
// blocks across XCDs. Contiguous z-slab per XCD keeps the gather halo in L2.

constexpr int D = 160;
constexpr int H = 192;
constexpr int W = 160;
constexpr int HW = H * W;        // 30720
constexpr int DHW = D * HW;      // 4915200
constexpr int NSTEPS = 7;

constexpr int BX = 32, BY = 8;   // block tile (x,y), z-tile = 1
constexpr int NTX = W / BX;      // 5
constexpr int NTY = H / BY;      // 24
constexpr int NTZ = D;           // 160
constexpr int NBLK = NTX * NTY * NTZ;   // 19200
constexpr int NXCD = 8;
constexpr int BLK_PER_XCD = NBLK / NXCD; // 2400

__global__ __launch_bounds__(256)
void vecint_step(const float* __restrict__ src, float* __restrict__ dst, float s) {
    // XCD-slab swizzle: HW round-robins blockIdx.x across the 8 XCDs, so give
    // XCD k the contiguous tile range [k*2400, (k+1)*2400) — a 20-plane slab.
    int bid   = blockIdx.x;
    int sid   = (bid & (NXCD - 1)) * BLK_PER_XCD + (bid >> 3);
    int tx    = sid % NTX;
    int t2    = sid / NTX;
    int ty    = t2 % NTY;
    int tz    = t2 / NTY;

    int w = tx * BX + threadIdx.x;
    int h = ty * BY + threadIdx.y;
    int d = tz;
    int p = d * HW + h * W + w;

    // Displacement at this voxel (3 channels, coalesced f32 loads).
    float vzf = src[p];
    float vyf = src[p + DHW];
    float vxf = src[p + 2 * DHW];
    double vz = (double)vzf, vy = (double)vyf, vx = (double)vxf;
    double sd = (double)s;

    // Unnormalized coords: (s*v + ident + 1)*0.5*(dim-1) = s*v*0.5*(dim-1) + idx
    double z = vz * (sd * 0.5 * (double)(D - 1)) + (double)d;
    double y = vy * (sd * 0.5 * (double)(H - 1)) + (double)h;
    double x = vx * (sd * 0.5 * (double)(W - 1)) + (double)w;

    double z0f = floor(z), y0f = floor(y), x0f = floor(x);
    int z0 = (int)z0f, y0 = (int)y0f, x0 = (int)x0f;
    int z1 = z0 + 1,   y1 = y0 + 1,   x1 = x0 + 1;
    double fz = z - z0f, fy = y - y0f, fx = x - x0f;

    // Zero-padding validity per axis index.
    bool zv0 = ((unsigned)z0 < (unsigned)D), zv1 = ((unsigned)z1 < (unsigned)D);
    bool yv0 = ((unsigned)y0 < (unsigned)H), yv1 = ((unsigned)y1 < (unsigned)H);
    bool xv0 = ((unsigned)x0 < (unsigned)W), xv1 = ((unsigned)x1 < (unsigned)W);

    // Clamped indices (loads always in-bounds; invalid corners get weight 0).
    int zc0 = min(max(z0, 0), D - 1), zc1 = min(max(z1, 0), D - 1);
    int yc0 = min(max(y0, 0), H - 1), yc1 = min(max(y1, 0), H - 1);
    int xc0 = min(max(x0, 0), W - 1), xc1 = min(max(x1, 0), W - 1);

    double wz0 = 1.0 - fz, wz1 = fz;
    double wy0 = 1.0 - fy, wy1 = fy;
    double wx0 = 1.0 - fx, wx1 = fx;

    double w000 = (zv0 && yv0 && xv0) ? wz0 * wy0 * wx0 : 0.0;
    double w001 = (zv0 && yv0 && xv1) ? wz0 * wy0 * wx1 : 0.0;
    double w010 = (zv0 && yv1 && xv0) ? wz0 * wy1 * wx0 : 0.0;
    double w011 = (zv0 && yv1 && xv1) ? wz0 * wy1 * wx1 : 0.0;
    double w100 = (zv1 && yv0 && xv0) ? wz1 * wy0 * wx0 : 0.0;
    double w101 = (zv1 && yv0 && xv1) ? wz1 * wy0 * wx1 : 0.0;
    double w110 = (zv1 && yv1 && xv0) ? wz1 * wy1 * wx0 : 0.0;
    double w111 = (zv1 && yv1 && xv1) ? wz1 * wy1 * wx1 : 0.0;

    int b00 = zc0 * HW + yc0 * W;
    int b01 = zc0 * HW + yc1 * W;
    int b10 = zc1 * HW + yc0 * W;
    int b11 = zc1 * HW + yc1 * W;

    int a000 = b00 + xc0, a001 = b00 + xc1;
    int a010 = b01 + xc0, a011 = b01 + xc1;
    int a100 = b10 + xc0, a101 = b10 + xc1;
    int a110 = b11 + xc0, a111 = b11 + xc1;

    double ctr[3] = {vz, vy, vx};
    #pragma unroll
    for (int c = 0; c < 3; ++c) {
        const float* sc = src + c * DHW;
        double acc = ctr[c];
        acc += w000 * (double)sc[a000];
        acc += w001 * (double)sc[a001];
        acc += w010 * (double)sc[a010];
        acc += w011 * (double)sc[a011];
        acc += w100 * (double)sc[a100];
        acc += w101 * (double)sc[a101];
        acc += w110 * (double)sc[a110];
        acc += w111 * (double)sc[a111];
        dst[c * DHW + p] = (float)(sd * acc);
    }
}

extern "C" void kernel_launch(void* const* d_in, const int* in_sizes, int n_in,
                              void* d_out, int out_size, void* d_ws, size_t ws_size,
                              hipStream_t stream) {
    const float* vin = (const float*)d_in[0];
    float* out = (float*)d_out;
    float* ws  = (float*)d_ws;

    const float s = 1.0f / 128.0f;  // 1/2^NSTEPS, exact power of 2

    dim3 block(BX, BY, 1);
    dim3 grid(NBLK, 1, 1);

    // Step 1: fold the initial scale in, read pristine input, write d_out.
    vecint_step<<<grid, block, 0, stream>>>(vin, out, s);

    // Steps 2..7: ping-pong d_out <-> d_ws; 6 more steps ends back in d_out.
    const float* srcs[6] = {out, ws, out, ws, out, ws};
    float*       dsts[6] = {ws, out, ws, out, ws, out};
    for (int i = 0; i < NSTEPS - 1; ++i) {
        vecint_step<<<grid, block, 0, stream>>>(srcs[i], dsts[i], 1.0f);
    }
}

// Round 4
// 564.964 us; speedup vs baseline: 2.2570x; 1.7274x over previous
//
#include <hip/hip_runtime.h>

// VecInt: scaling-and-squaring integration of a stationary velocity field.
// vec' = vec/2^7; repeat 7x: vec = vec + grid_sample3d(vec, vec + ident).
// Fixed problem shape: (1, 3, 160, 192, 160) float32.
//
// Numerics: per-step arithmetic in double, f32 stores (absmax 4.39e-3 vs
// 5.16e-3 threshold). Accumulation order is kept bitwise-identical across
// kernel variants.
//
// Perf model (R3 post-mortem): the field is white noise and doubles each
// step, so late-step gather offsets are ~N(0, 10-40 voxels) and uncorrelated
// per lane -> 24 fully-divergent dword gathers/voxel = 24*64 L1/TA lookups
// per wave. Measured ~170 us/step matches a ~1 lookup/cycle/CU bound.
// Fix: AoS4 (float4 voxel) layout in workspace -> 2 aligned dwordx4 loads
// cover (x0,x1)x3ch per corner row: 8 lookups/voxel instead of 24.

constexpr int D = 160;
constexpr int H = 192;
constexpr int W = 160;
constexpr int HW = H * W;        // 30720
constexpr int DHW = D * HW;      // 4915200
constexpr int NSTEPS = 7;

constexpr int BX = 32, BY = 8;   // block tile (x,y), z-tile = 1
constexpr int NTX = W / BX;      // 5
constexpr int NTY = H / BY;      // 24
constexpr int NTZ = D;           // 160
constexpr int NBLK = NTX * NTY * NTZ;   // 19200
constexpr int NXCD = 8;
constexpr int BLK_PER_XCD = NBLK / NXCD; // 2400

__device__ __forceinline__ void decode_tile(int bid, int& w, int& h, int& d) {
    // XCD-slab swizzle: HW round-robins blockIdx.x across 8 XCDs; give XCD k
    // the contiguous tile range [k*2400,(k+1)*2400) — a 20-plane z-slab.
    int sid = (bid & (NXCD - 1)) * BLK_PER_XCD + (bid >> 3);
    int tx  = sid % NTX;
    int t2  = sid / NTX;
    int ty  = t2 % NTY;
    int tz  = t2 / NTY;
    w = tx * BX + threadIdx.x;
    h = ty * BY + threadIdx.y;
    d = tz;
}

// ---------- AoS4 path (float4 voxels in workspace) ----------

__global__ __launch_bounds__(256)
void soa_to_aos4(const float* __restrict__ src, float4* __restrict__ dst) {
    int p = blockIdx.x * blockDim.x + threadIdx.x;
    if (p >= DHW) return;
    float4 v;
    v.x = src[p];
    v.y = src[p + DHW];
    v.z = src[p + 2 * DHW];
    v.w = 0.0f;
    dst[p] = v;
}

__global__ __launch_bounds__(256)
void aos4_to_soa(const float4* __restrict__ src, float* __restrict__ dst) {
    int p = blockIdx.x * blockDim.x + threadIdx.x;
    if (p >= DHW) return;
    float4 v = src[p];
    dst[p]           = v.x;
    dst[p + DHW]     = v.y;
    dst[p + 2 * DHW] = v.z;
}

__global__ __launch_bounds__(256)
void vecint_step4(const float4* __restrict__ src, float4* __restrict__ dst, float s) {
    int w, h, d;
    decode_tile(blockIdx.x, w, h, d);
    int p = d * HW + h * W + w;

    float4 ctr = src[p];
    double vz = (double)ctr.x, vy = (double)ctr.y, vx = (double)ctr.z;
    double sd = (double)s;

    // Unnormalized coords: s*v*0.5*(dim-1) + idx
    double z = vz * (sd * 0.5 * (double)(D - 1)) + (double)d;
    double y = vy * (sd * 0.5 * (double)(H - 1)) + (double)h;
    double x = vx * (sd * 0.5 * (double)(W - 1)) + (double)w;

    double z0f = floor(z), y0f = floor(y), x0f = floor(x);
    int z0 = (int)z0f, y0 = (int)y0f, x0 = (int)x0f;
    int z1 = z0 + 1,   y1 = y0 + 1,   x1 = x0 + 1;
    double fz = z - z0f, fy = y - y0f, fx = x - x0f;

    bool zv0 = ((unsigned)z0 < (unsigned)D), zv1 = ((unsigned)z1 < (unsigned)D);
    bool yv0 = ((unsigned)y0 < (unsigned)H), yv1 = ((unsigned)y1 < (unsigned)H);
    bool xv0 = ((unsigned)x0 < (unsigned)W), xv1 = ((unsigned)x1 < (unsigned)W);

    int zc0 = min(max(z0, 0), D - 1), zc1 = min(max(z1, 0), D - 1);
    int yc0 = min(max(y0, 0), H - 1), yc1 = min(max(y1, 0), H - 1);
    int xc0 = min(max(x0, 0), W - 1), xc1 = min(max(x1, 0), W - 1);

    double wz0 = 1.0 - fz, wz1 = fz;
    double wy0 = 1.0 - fy, wy1 = fy;
    double wx0 = 1.0 - fx, wx1 = fx;

    double w000 = (zv0 && yv0 && xv0) ? wz0 * wy0 * wx0 : 0.0;
    double w001 = (zv0 && yv0 && xv1) ? wz0 * wy0 * wx1 : 0.0;
    double w010 = (zv0 && yv1 && xv0) ? wz0 * wy1 * wx0 : 0.0;
    double w011 = (zv0 && yv1 && xv1) ? wz0 * wy1 * wx1 : 0.0;
    double w100 = (zv1 && yv0 && xv0) ? wz1 * wy0 * wx0 : 0.0;
    double w101 = (zv1 && yv0 && xv1) ? wz1 * wy0 * wx1 : 0.0;
    double w110 = (zv1 && yv1 && xv0) ? wz1 * wy1 * wx0 : 0.0;
    double w111 = (zv1 && yv1 && xv1) ? wz1 * wy1 * wx1 : 0.0;

    // x-pair base: clamp so both f0=src[r+bx] and f1=src[r+bx+1] are in-row.
    // Branch-free selection reproduces exactly sc[clamped x0], sc[clamped x1].
    int bx = min(max(x0, 0), W - 2);
    bool s0hi = (xc0 != bx);   // x0 clamped to W-1: take f1
    bool s1lo = (xc1 == bx);   // x1 clamped to 0:   take f0

    int r00 = zc0 * HW + yc0 * W;
    int r01 = zc0 * HW + yc1 * W;
    int r10 = zc1 * HW + yc0 * W;
    int r11 = zc1 * HW + yc1 * W;

    float4 f00a = src[r00 + bx], f00b = src[r00 + bx + 1];
    float4 f01a = src[r01 + bx], f01b = src[r01 + bx + 1];
    float4 f10a = src[r10 + bx], f10b = src[r10 + bx + 1];
    float4 f11a = src[r11 + bx], f11b = src[r11 + bx + 1];

    float4 x000 = s0hi ? f00b : f00a;  float4 x001 = s1lo ? f00a : f00b;
    float4 x010 = s0hi ? f01b : f01a;  float4 x011 = s1lo ? f01a : f01b;
    float4 x100 = s0hi ? f10b : f10a;  float4 x101 = s1lo ? f10a : f10b;
    float4 x110 = s0hi ? f11b : f11a;  float4 x111 = s1lo ? f11a : f11b;

    float4 o;
    {
        double acc = vz;
        acc += w000 * (double)x000.x; acc += w001 * (double)x001.x;
        acc += w010 * (double)x010.x; acc += w011 * (double)x011.x;
        acc += w100 * (double)x100.x; acc += w101 * (double)x101.x;
        acc += w110 * (double)x110.x; acc += w111 * (double)x111.x;
        o.x = (float)(sd * acc);
    }
    {
        double acc = vy;
        acc += w000 * (double)x000.y; acc += w001 * (double)x001.y;
        acc += w010 * (double)x010.y; acc += w011 * (double)x011.y;
        acc += w100 * (double)x100.y; acc += w101 * (double)x101.y;
        acc += w110 * (double)x110.y; acc += w111 * (double)x111.y;
        o.y = (float)(sd * acc);
    }
    {
        double acc = vx;
        acc += w000 * (double)x000.z; acc += w001 * (double)x001.z;
        acc += w010 * (double)x010.z; acc += w011 * (double)x011.z;
        acc += w100 * (double)x100.z; acc += w101 * (double)x101.z;
        acc += w110 * (double)x110.z; acc += w111 * (double)x111.z;
        o.z = (float)(sd * acc);
    }
    o.w = 0.0f;
    dst[p] = o;
}

// ---------- Fallback SoA path (R3 kernel) ----------

__global__ __launch_bounds__(256)
void vecint_step(const float* __restrict__ src, float* __restrict__ dst, float s) {
    int w, h, d;
    decode_tile(blockIdx.x, w, h, d);
    int p = d * HW + h * W + w;

    double vz = (double)src[p];
    double vy = (double)src[p + DHW];
    double vx = (double)src[p + 2 * DHW];
    double sd = (double)s;

    double z = vz * (sd * 0.5 * (double)(D - 1)) + (double)d;
    double y = vy * (sd * 0.5 * (double)(H - 1)) + (double)h;
    double x = vx * (sd * 0.5 * (double)(W - 1)) + (double)w;

    double z0f = floor(z), y0f = floor(y), x0f = floor(x);
    int z0 = (int)z0f, y0 = (int)y0f, x0 = (int)x0f;
    int z1 = z0 + 1,   y1 = y0 + 1,   x1 = x0 + 1;
    double fz = z - z0f, fy = y - y0f, fx = x - x0f;

    bool zv0 = ((unsigned)z0 < (unsigned)D), zv1 = ((unsigned)z1 < (unsigned)D);
    bool yv0 = ((unsigned)y0 < (unsigned)H), yv1 = ((unsigned)y1 < (unsigned)H);
    bool xv0 = ((unsigned)x0 < (unsigned)W), xv1 = ((unsigned)x1 < (unsigned)W);

    int zc0 = min(max(z0, 0), D - 1), zc1 = min(max(z1, 0), D - 1);
    int yc0 = min(max(y0, 0), H - 1), yc1 = min(max(y1, 0), H - 1);
    int xc0 = min(max(x0, 0), W - 1), xc1 = min(max(x1, 0), W - 1);

    double wz0 = 1.0 - fz, wz1 = fz;
    double wy0 = 1.0 - fy, wy1 = fy;
    double wx0 = 1.0 - fx, wx1 = fx;

    double w000 = (zv0 && yv0 && xv0) ? wz0 * wy0 * wx0 : 0.0;
    double w001 = (zv0 && yv0 && xv1) ? wz0 * wy0 * wx1 : 0.0;
    double w010 = (zv0 && yv1 && xv0) ? wz0 * wy1 * wx0 : 0.0;
    double w011 = (zv0 && yv1 && xv1) ? wz0 * wy1 * wx1 : 0.0;
    double w100 = (zv1 && yv0 && xv0) ? wz1 * wy0 * wx0 : 0.0;
    double w101 = (zv1 && yv0 && xv1) ? wz1 * wy0 * wx1 : 0.0;
    double w110 = (zv1 && yv1 && xv0) ? wz1 * wy1 * wx0 : 0.0;
    double w111 = (zv1 && yv1 && xv1) ? wz1 * wy1 * wx1 : 0.0;

    int b00 = zc0 * HW + yc0 * W;
    int b01 = zc0 * HW + yc1 * W;
    int b10 = zc1 * HW + yc0 * W;
    int b11 = zc1 * HW + yc1 * W;

    int a000 = b00 + xc0, a001 = b00 + xc1;
    int a010 = b01 + xc0, a011 = b01 + xc1;
    int a100 = b10 + xc0, a101 = b10 + xc1;
    int a110 = b11 + xc0, a111 = b11 + xc1;

    double ctr[3] = {vz, vy, vx};
    #pragma unroll
    for (int c = 0; c < 3; ++c) {
        const float* sc = src + c * DHW;
        double acc = ctr[c];
        acc += w000 * (double)sc[a000];
        acc += w001 * (double)sc[a001];
        acc += w010 * (double)sc[a010];
        acc += w011 * (double)sc[a011];
        acc += w100 * (double)sc[a100];
        acc += w101 * (double)sc[a101];
        acc += w110 * (double)sc[a110];
        acc += w111 * (double)sc[a111];
        dst[c * DHW + p] = (float)(sd * acc);
    }
}

extern "C" void kernel_launch(void* const* d_in, const int* in_sizes, int n_in,
                              void* d_out, int out_size, void* d_ws, size_t ws_size,
                              hipStream_t stream) {
    const float* vin = (const float*)d_in[0];
    float* out = (float*)d_out;

    const float s = 1.0f / 128.0f;  // 1/2^NSTEPS, exact power of 2

    dim3 tile_block(BX, BY, 1);
    dim3 tile_grid(NBLK, 1, 1);
    dim3 lin_block(256);
    dim3 lin_grid(DHW / 256);

    const size_t aos4_bytes = (size_t)DHW * sizeof(float4);

    if (ws_size >= 2 * aos4_bytes) {
        // AoS4 path: A = raw input repacked; ping-pong A<->B; 7 steps end in B.
        float4* A = (float4*)d_ws;
        float4* B = A + DHW;

        soa_to_aos4<<<lin_grid, lin_block, 0, stream>>>(vin, A);
        vecint_step4<<<tile_grid, tile_block, 0, stream>>>(A, B, s);  // step 1 folds scale
        const float4* s4[6] = {B, A, B, A, B, A};
        float4*       d4[6] = {A, B, A, B, A, B};
        for (int i = 0; i < NSTEPS - 1; ++i)
            vecint_step4<<<tile_grid, tile_block, 0, stream>>>(s4[i], d4[i], 1.0f);
        aos4_to_soa<<<lin_grid, lin_block, 0, stream>>>(B, out);
    } else {
        // Fallback: SoA ping-pong d_out <-> d_ws (R3 path).
        float* ws = (float*)d_ws;
        vecint_step<<<tile_grid, tile_block, 0, stream>>>(vin, out, s);
        const float* srcs[6] = {out, ws, out, ws, out, ws};
        float*       dsts[6] = {ws, out, ws, out, ws, out};
        for (int i = 0; i < NSTEPS - 1; ++i)
            vecint_step<<<tile_grid, tile_block, 0, stream>>>(srcs[i], dsts[i], 1.0f);
    }
}